// Round 5
// baseline (284.026 us; speedup 1.0000x reference)
//
#include <hip/hip_runtime.h>
#include <math.h>

#define Hd 192
#define Wd 640
#define HWp (Hd * Wd)
#define NCLS 3
#define KTOP 50
#define NB 32
#define NPL (NB * NCLS)      // 96 planes
#define SPR 40               // 16-px strips per row
#define TSTR (Hd * SPR)      // 7680 strips per plane
#define NSUB 6               // sub-blocks per plane
#define SSTR (TSTR / NSUB)   // 1280 strips per sub-block
#define CAPS 512             // per-sub candidate cap (E~98, 29 sigma)
#define CAP 2048             // decode-fallback candidate cap
#define RBK 256              // rank buckets
#define GPR 160              // 4-px groups per row (fallback scanner)
#define GPP (HWp / 4)        // 30720 groups per plane (fallback scanner)
#define NMERGE (NCLS * NSUB * KTOP)  // 900
#define TH_F 0.995f
#define PI_F 3.14159265358979f

// ---- workspace layout (coherence via the single kernel boundary only) ----
#define OFF_SSC 0            // sub_sc: [NPL*NSUB][64] floats = 147456 B
#define OFF_SPI 0x40000      // sub_pi: [NPL*NSUB][64] ints
#define OFF_SCNT 0x80000     // sub_cnt: [NPL*NSUB] ints

__device__ inline float fmax3(float a, float b, float c) {
  return fmaxf(fmaxf(a, b), c);
}

// key = (bits << 32) | ~idx : strict u64 '>' == (value desc, idx asc).
__device__ inline unsigned long long mk_key(unsigned int bits, int idx) {
  return ((unsigned long long)bits << 32) | (unsigned int)~idx;
}

// Monotone bucket over value bits; ~uniform on [0.995, 1.0); clamped outside.
__device__ inline int bucket_of(unsigned int bits) {
  const unsigned int base = __float_as_uint(TH_F);
  if (bits <= base) return 0;
  unsigned int d = (bits - base) >> 9;
  return d > 255u ? 255 : (int)d;
}

// Composed merge key: (score bits)<<19 | (2-cls)<<17 | (idx ^ 0x1FFFF).
// Strict u64 '>' == (score desc, cls asc, idx asc) — the reference's
// flattened-position tie order. idx < 122880 < 2^17.
__device__ inline unsigned long long mk_key19(unsigned int bits, int cls, int idx) {
  return ((unsigned long long)bits << 19) |
         ((unsigned long long)(2 - cls) << 17) |
         (unsigned long long)((idx ^ 0x1FFFF) & 0x1FFFF);
}

// ---------------------------------------------------------------------------
// 16-px row segment, all named fields (registers only — no arrays).
// ---------------------------------------------------------------------------
struct Row16 {
  float4 q0, q1, q2, q3;
  float l, r;
};

__device__ inline Row16 load_row16(const float* __restrict__ rp, int x0, bool valid) {
  Row16 o;
  if (valid) {
    o.q0 = *(const float4*)(rp);
    o.q1 = *(const float4*)(rp + 4);
    o.q2 = *(const float4*)(rp + 8);
    o.q3 = *(const float4*)(rp + 12);
    o.l = (x0 > 0) ? rp[-1] : -INFINITY;
    o.r = (x0 + 16 < Wd) ? rp[16] : -INFINITY;
  } else {
    o.q0.x = o.q0.y = o.q0.z = o.q0.w = -INFINITY;
    o.q1 = o.q0; o.q2 = o.q0; o.q3 = o.q0;
    o.l = -INFINITY; o.r = -INFINITY;
  }
  return o;
}

__device__ inline float4 max3v(const float4 a, const float4 b, const float4 c) {
  float4 o;
  o.x = fmax3(a.x, b.x, c.x);
  o.y = fmax3(a.y, b.y, c.y);
  o.z = fmax3(a.z, b.z, c.z);
  o.w = fmax3(a.w, b.w, c.w);
  return o;
}

// Visit every >=TH 8-neighborhood peak in one 16-px strip.
template <typename F>
__device__ inline void strip_peaks(const float* __restrict__ hp, int strip, F&& f) {
  const int y = strip / SPR;
  const int x0 = (strip - y * SPR) * 16;
  const float* pm = hp + y * Wd + x0;
  const Row16 m = load_row16(pm, x0, true);
  const Row16 t = load_row16(pm - Wd, x0, y > 0);
  const Row16 b = load_row16(pm + Wd, x0, y < Hd - 1);
  const float cl = fmax3(t.l, m.l, b.l);
  const float cr = fmax3(t.r, m.r, b.r);
  const float4 c0 = max3v(t.q0, m.q0, b.q0);
  const float4 c1 = max3v(t.q1, m.q1, b.q1);
  const float4 c2 = max3v(t.q2, m.q2, b.q2);
  const float4 c3 = max3v(t.q3, m.q3, b.q3);
  const int base = y * Wd + x0;
#define EMIT(V, W0, W1, W2, J)                                       \
  if ((V) >= TH_F && (V) == fmax3((W0), (W1), (W2)))                 \
    f(__float_as_uint(V), base + (J));
  EMIT(m.q0.x, cl,   c0.x, c0.y, 0)
  EMIT(m.q0.y, c0.x, c0.y, c0.z, 1)
  EMIT(m.q0.z, c0.y, c0.z, c0.w, 2)
  EMIT(m.q0.w, c0.z, c0.w, c1.x, 3)
  EMIT(m.q1.x, c0.w, c1.x, c1.y, 4)
  EMIT(m.q1.y, c1.x, c1.y, c1.z, 5)
  EMIT(m.q1.z, c1.y, c1.z, c1.w, 6)
  EMIT(m.q1.w, c1.z, c1.w, c2.x, 7)
  EMIT(m.q2.x, c1.w, c2.x, c2.y, 8)
  EMIT(m.q2.y, c2.x, c2.y, c2.z, 9)
  EMIT(m.q2.z, c2.y, c2.z, c2.w, 10)
  EMIT(m.q2.w, c2.z, c2.w, c3.x, 11)
  EMIT(m.q3.x, c2.w, c3.x, c3.y, 12)
  EMIT(m.q3.y, c3.x, c3.y, c3.z, 13)
  EMIT(m.q3.z, c3.y, c3.z, c3.w, 14)
  EMIT(m.q3.w, c3.z, c3.w, cr,   15)
#undef EMIT
}

// ---------------------------------------------------------------------------
// Whole-plane 4-px-group peak scanner (decode's exact-rescan fallback only;
// visits ALL peaks, no threshold).
// ---------------------------------------------------------------------------
template <typename F>
__device__ inline void peaks_in_group(const float* __restrict__ p, int g, F&& f) {
  const int y = g / GPR;
  const int x0 = (g - y * GPR) * 4;
  const float* rm = p + y * Wd + x0;
  const float4 mq = *(const float4*)rm;
  const float ml = (x0 > 0) ? rm[-1] : -INFINITY;
  const float mr = (x0 + 4 < Wd) ? rm[4] : -INFINITY;
  float4 tq; float tl, tr;
  if (y > 0) {
    const float* rt = rm - Wd;
    tq = *(const float4*)rt;
    tl = (x0 > 0) ? rt[-1] : -INFINITY;
    tr = (x0 + 4 < Wd) ? rt[4] : -INFINITY;
  } else {
    tq.x = tq.y = tq.z = tq.w = -INFINITY; tl = -INFINITY; tr = -INFINITY;
  }
  float4 bq; float bl, br;
  if (y < Hd - 1) {
    const float* rb = rm + Wd;
    bq = *(const float4*)rb;
    bl = (x0 > 0) ? rb[-1] : -INFINITY;
    br = (x0 + 4 < Wd) ? rb[4] : -INFINITY;
  } else {
    bq.x = bq.y = bq.z = bq.w = -INFINITY; bl = -INFINITY; br = -INFINITY;
  }
  const float c0 = fmax3(tl, ml, bl);
  const float c1 = fmax3(tq.x, mq.x, bq.x);
  const float c2 = fmax3(tq.y, mq.y, bq.y);
  const float c3 = fmax3(tq.z, mq.z, bq.z);
  const float c4 = fmax3(tq.w, mq.w, bq.w);
  const float c5 = fmax3(tr, mr, br);
  const int base = y * Wd + x0;
  if (mq.x == fmax3(c0, c1, c2)) f(__float_as_uint(mq.x), base + 0);
  if (mq.y == fmax3(c1, c2, c3)) f(__float_as_uint(mq.y), base + 1);
  if (mq.z == fmax3(c2, c3, c4)) f(__float_as_uint(mq.z), base + 2);
  if (mq.w == fmax3(c3, c4, c5)) f(__float_as_uint(mq.w), base + 3);
}

template <typename F>
__device__ inline void for_each_peak_plane(const float* __restrict__ p, int tid,
                                           int nth, F&& f) {
  for (int g = tid; g < GPP; g += nth) peaks_in_group(p, g, f);
}

__device__ inline void inv3(const float* m, float* o) {
  float a = m[0], b = m[1], c = m[2];
  float d = m[3], e = m[4], f = m[5];
  float g = m[6], h = m[7], i = m[8];
  float A = e * i - f * h;
  float B = -(d * i - f * g);
  float C = d * h - e * g;
  float det = a * A + b * B + c * C;
  float id = 1.0f / det;
  o[0] = A * id;            o[1] = -(b * i - c * h) * id; o[2] = (b * f - c * e) * id;
  o[3] = B * id;            o[4] = (a * i - c * g) * id;  o[5] = -(a * f - c * d) * id;
  o[6] = C * id;            o[7] = -(a * h - b * g) * id; o[8] = (a * e - b * d) * id;
}

__device__ inline float wrap_pi(float a) {
  if (a > PI_F) return a - 2.0f * PI_F;
  if (a < -PI_F) return a + 2.0f * PI_F;
  return a;
}

__constant__ float DIM_REF_C[9] = {3.88f, 1.63f, 1.53f,
                                   0.84f, 1.76f, 0.66f,
                                   1.78f, 1.52f, 1.78f};

// ---------------------------------------------------------------------------
// Kernel 1: fused scan+rank. 576 blocks (plane-sixths) x 256 threads, 5
// strips/thread. Candidates collected in LDS, counting-sort ranked in-block,
// only the sub-top-50 hits HBM. No cross-block traffic of any kind.
// ---------------------------------------------------------------------------
__global__ __launch_bounds__(256) void scanrank_kernel(
    const float* __restrict__ heat,
    float* __restrict__ ssc,    // [NPL*NSUB][64]
    int* __restrict__ spi,      // [NPL*NSUB][64]
    int* __restrict__ scnt) {   // [NPL*NSUB]
  const int blk = blockIdx.x;
  const int tid = threadIdx.x;
  const int plane = blk / NSUB;
  const int sub = blk - plane * NSUB;
  const float* hp = heat + (size_t)plane * HWp;
  const int sbase = sub * SSTR;

  __shared__ unsigned long long s_key[CAPS];   // 4 KB raw candidates
  __shared__ unsigned long long c_key[CAPS];   // 4 KB grouped (aliases hist)
  __shared__ int cnt[RBK], suf[RBK], cur[RBK];
  __shared__ int s_n, s_B, s_above, s_T;

  if (tid == 0) s_n = 0;
  __syncthreads();

  // ---- collect >=TH peaks over this block's 1280 strips ----
  for (int it = 0; it < SSTR / 256; ++it) {
    const int strip = sbase + it * 256 + tid;
    strip_peaks(hp, strip, [&](unsigned int bits, int idx) {
      int slot = atomicAdd(&s_n, 1);
      if (slot < CAPS) s_key[slot] = mk_key(bits, idx);
    });
  }
  __syncthreads();
  int n = s_n;

  if (n > CAPS) {
    // Overflow (29-sigma event): raise the threshold via a two-level
    // histogram over [TH, 1.0) and recollect. Exact for the top-50.
    unsigned int* hist = (unsigned int*)c_key;   // 1024 u32 = 4 KB
    const unsigned int THB = __float_as_uint(TH_F);
    for (int i = tid; i < 1024; i += 256) hist[i] = 0;
    __syncthreads();
    for (int it = 0; it < SSTR / 256; ++it) {
      const int strip = sbase + it * 256 + tid;
      strip_peaks(hp, strip, [&](unsigned int bits, int idx) {
        atomicAdd(&hist[(bits - THB) >> 7], 1u);   // <= 655
      });
    }
    __syncthreads();
    if (tid == 0) {
      int acc = 0, res = 0, above = 0;
      for (int q = 655; q >= 0; --q) {
        int cc = (int)hist[q];
        if (acc + cc >= KTOP) { res = q; above = acc; break; }
        acc += cc;
      }
      s_B = res; s_above = above;
    }
    __syncthreads();
    const int Bc = s_B;
    for (int i = tid; i < 1024; i += 256) hist[i] = 0;
    __syncthreads();
    for (int it = 0; it < SSTR / 256; ++it) {
      const int strip = sbase + it * 256 + tid;
      strip_peaks(hp, strip, [&](unsigned int bits, int idx) {
        if ((int)((bits - THB) >> 7) == Bc)
          atomicAdd(&hist[(bits - THB) & 127], 1u);
      });
    }
    __syncthreads();
    if (tid == 0) {
      int acc = s_above, S = 0;
      for (int sb = 127; sb >= 0; --sb) {
        int cc = (int)hist[sb];
        if (acc + cc >= KTOP) { S = sb; break; }
        acc += cc;
      }
      s_T = (int)(THB + ((unsigned int)Bc << 7) + (unsigned int)S);
      s_n = 0;
    }
    __syncthreads();
    const unsigned int T = (unsigned int)s_T;
    for (int it = 0; it < SSTR / 256; ++it) {
      const int strip = sbase + it * 256 + tid;
      strip_peaks(hp, strip, [&](unsigned int bits, int idx) {
        if (bits >= T) {
          int slot = atomicAdd(&s_n, 1);
          if (slot < CAPS) s_key[slot] = mk_key(bits, idx);
        }
      });
    }
    __syncthreads();
    n = s_n < CAPS ? s_n : CAPS;
  }

  // ---- O(n) counting-sort rank: (value desc, idx asc). ----
  cnt[tid] = 0;
  cur[tid] = 0;
  __syncthreads();
  for (int i = tid; i < n; i += 256)
    atomicAdd(&cnt[bucket_of((unsigned int)(s_key[i] >> 32))], 1);
  __syncthreads();
  suf[tid] = cnt[tid];
  __syncthreads();
#pragma unroll
  for (int d = 1; d < RBK; d <<= 1) {
    const int v = (tid + d < RBK) ? suf[tid + d] : 0;
    __syncthreads();
    suf[tid] += v;
    __syncthreads();
  }
  {
    const int excl = suf[tid] - cnt[tid];   // keys in buckets > tid
    __syncthreads();
    suf[tid] = excl;
  }
  __syncthreads();
  for (int i = tid; i < n; i += 256) {
    const unsigned long long k = s_key[i];
    const int bq = bucket_of((unsigned int)(k >> 32));
    const int slot = suf[bq] + atomicAdd(&cur[bq], 1);
    c_key[slot] = k;
  }
  __syncthreads();
  float* psc = ssc + blk * 64;
  int* ppi = spi + blk * 64;
  for (int i = tid; i < n; i += 256) {
    const unsigned long long k = c_key[i];
    const int bq = bucket_of((unsigned int)(k >> 32));
    const int st = suf[bq];
    const int nb = cnt[bq];
    int rank = st;
    for (int tt = st; tt < st + nb; ++tt) rank += (c_key[tt] > k);
    if (rank < KTOP) {
      psc[rank] = __uint_as_float((unsigned int)(k >> 32));
      ppi[rank] = (int)~((unsigned int)k);
    }
  }
  for (int s2 = n + tid; s2 < KTOP; s2 += 256) {
    psc[s2] = 0.0f;
    ppi[s2] = 0;
  }
  if (tid == 0) scnt[blk] = n;
}

// ---------------------------------------------------------------------------
// Kernel 2: merge + batch top-50 + 3D decode. 32 blocks x 256 threads.
// Per-class top-50 FIRST (reference tie semantics), then batch 150->50.
// ---------------------------------------------------------------------------
__global__ __launch_bounds__(256) void decode_kernel(
    const float* __restrict__ heat,
    const float* __restrict__ ssc,
    const int* __restrict__ spi,
    const int* __restrict__ scnt,
    const float* __restrict__ regr,      // [B][8][HWp]
    const float* __restrict__ trans_mat, // [B][3][3]
    const float* __restrict__ K_mat,     // [B][3][3]
    const float* __restrict__ img_size,  // [B][2]
    float* __restrict__ out) {           // [B*50][14]
  const int b = blockIdx.x;
  const int tid = threadIdx.x;

  __shared__ unsigned long long d_keys[NMERGE];     // 7.2 KB merged keys
  __shared__ unsigned long long f_keys[NCLS * KTOP];
  __shared__ unsigned char d_in[NMERGE];
  __shared__ int hb[NCLS][RBK];
  __shared__ int s_bq[NCLS];
  __shared__ int s_ct[NCLS];
  __shared__ int sel[KTOP];
  // fallback scratch (exact whole-plane rescan; never fires on this data)
  __shared__ unsigned long long s_key[CAP];         // 16 KB
  __shared__ unsigned long long c_key[CAP];         // 16 KB (hist alias)
  __shared__ int cnt[RBK], suf[RBK], cur[RBK];
  __shared__ int s_fbB, s_fbAbove, s_fbT, s_fbCnt;

  // true per-class >=TH candidate totals
  if (tid < NCLS) {
    int t = 0;
    for (int s = 0; s < NSUB; ++s) t += scnt[(b * NCLS + tid) * NSUB + s];
    s_ct[tid] = t;
  }
  __syncthreads();

  // build merged composed keys from the 18 sub-top-50 lists
  for (int i = tid; i < NMERGE; i += 256) {
    const int c = i / (NSUB * KTOP);
    const int rem = i - c * (NSUB * KTOP);
    const int s = rem / KTOP;
    const int k2 = rem - s * KTOP;
    const int sb = (b * NCLS + c) * NSUB + s;
    const float v = ssc[sb * 64 + k2];
    const int idx = spi[sb * 64 + k2];
    d_keys[i] = mk_key19(__float_as_uint(v), c, idx);
  }
  __syncthreads();

  // per-class exactness fallback: plane has <50 peaks >= TH -> exact rescan
  for (int c = 0; c < NCLS; ++c) {
    if (s_ct[c] < KTOP) {
      const float* hp = heat + (size_t)(b * NCLS + c) * HWp;
      unsigned int* fb_hist = (unsigned int*)c_key;
      for (int i = tid; i < 1024; i += 256) fb_hist[i] = 0;
      __syncthreads();
      for_each_peak_plane(hp, tid, 256, [&](unsigned int bits, int idx) {
        unsigned int bkt = bits >> 20; if (bkt > 1023u) bkt = 1023u;
        atomicAdd(&fb_hist[bkt], 1u);
      });
      __syncthreads();
      if (tid == 0) {
        int acc = 0, Bs = -1;
        for (int bkt = 1023; bkt >= 0; --bkt) {
          int cc = (int)fb_hist[bkt];
          if (acc + cc >= KTOP) { Bs = bkt; s_fbAbove = acc; break; }
          acc += cc;
        }
        s_fbB = Bs;
        if (Bs < 0) s_fbAbove = acc;
      }
      __syncthreads();
      const int Bs = s_fbB;
      unsigned int T;
      if (Bs < 0) {
        T = 0;  // fewer than 50 peaks total: take them all
      } else {
        for (int i = tid; i < 1024; i += 256) fb_hist[i] = 0;
        __syncthreads();
        for_each_peak_plane(hp, tid, 256, [&](unsigned int bits, int idx) {
          unsigned int bkt = bits >> 20; if (bkt > 1023u) bkt = 1023u;
          if ((int)bkt == Bs) atomicAdd(&fb_hist[(bits >> 10) & 1023], 1u);
        });
        __syncthreads();
        if (tid == 0) {
          int acc = s_fbAbove, Ss = 0;
          for (int sb = 1023; sb >= 0; --sb) {
            int cc = (int)fb_hist[sb];
            if (acc + cc >= KTOP) { Ss = sb; break; }
            acc += cc;
          }
          s_fbT = (int)(((unsigned int)Bs << 20) | ((unsigned int)Ss << 10));
        }
        __syncthreads();
        T = (unsigned int)s_fbT;
      }
      if (tid == 0) s_fbCnt = 0;
      __syncthreads();
      for_each_peak_plane(hp, tid, 256, [&](unsigned int bits, int idx) {
        if (bits >= T) {
          int slot = atomicAdd(&s_fbCnt, 1);
          if (slot < CAP) s_key[slot] = mk_key(bits, idx);
        }
      });
      __syncthreads();
      const int M = s_fbCnt < CAP ? s_fbCnt : CAP;
      // rank M keys, write class-c top-50 into its d_keys slice
      cnt[tid] = 0; cur[tid] = 0;
      __syncthreads();
      for (int i = tid; i < M; i += 256)
        atomicAdd(&cnt[bucket_of((unsigned int)(s_key[i] >> 32))], 1);
      __syncthreads();
      suf[tid] = cnt[tid];
      __syncthreads();
#pragma unroll
      for (int d = 1; d < RBK; d <<= 1) {
        const int v = (tid + d < RBK) ? suf[tid + d] : 0;
        __syncthreads();
        suf[tid] += v;
        __syncthreads();
      }
      {
        const int excl = suf[tid] - cnt[tid];
        __syncthreads();
        suf[tid] = excl;
      }
      __syncthreads();
      for (int i = tid; i < M; i += 256) {
        const unsigned long long k = s_key[i];
        const int bq = bucket_of((unsigned int)(k >> 32));
        const int slot = suf[bq] + atomicAdd(&cur[bq], 1);
        c_key[slot] = k;
      }
      __syncthreads();
      for (int i = tid; i < NMERGE / NCLS; i += 256)   // clear class slice
        d_keys[c * (NSUB * KTOP) + i] = mk_key19(0u, c, 0);
      __syncthreads();
      for (int i = tid; i < M; i += 256) {
        const unsigned long long k = c_key[i];
        const int bq = bucket_of((unsigned int)(k >> 32));
        const int st = suf[bq];
        const int nb = cnt[bq];
        int rank = st;
        for (int tt = st; tt < st + nb; ++tt) rank += (c_key[tt] > k);
        if (rank < KTOP)
          d_keys[c * (NSUB * KTOP) + rank] =
              mk_key19((unsigned int)(k >> 32), c, (int)~((unsigned int)k));
      }
      __syncthreads();
    }
  }

  // ---- stage A: per-class top-50 (bucket-threshold prune + exact rank) ----
  for (int i = tid; i < NCLS * RBK; i += 256) ((int*)hb)[i] = 0;
  __syncthreads();
  for (int i = tid; i < NMERGE; i += 256) {
    const int c = i / (NSUB * KTOP);
    atomicAdd(&hb[c][bucket_of((unsigned int)(d_keys[i] >> 19))], 1);
  }
  __syncthreads();
  if (tid < NCLS) {
    int acc = 0, res = 0;
    for (int q = RBK - 1; q >= 0; --q) {
      acc += hb[tid][q];
      if (acc >= KTOP) { res = q; break; }
    }
    s_bq[tid] = res;
  }
  __syncthreads();
  for (int i = tid; i < NMERGE; i += 256) {
    const int c = i / (NSUB * KTOP);
    d_in[i] = bucket_of((unsigned int)(d_keys[i] >> 19)) >= s_bq[c];
  }
  __syncthreads();
  for (int i = tid; i < NMERGE; i += 256) {
    if (!d_in[i]) continue;
    const int c = i / (NSUB * KTOP);
    const int lo = c * (NSUB * KTOP), hi = lo + (NSUB * KTOP);
    const unsigned long long k = d_keys[i];
    int rank = 0;
    for (int j = lo; j < hi; ++j) {
      if (!d_in[j]) continue;
      const unsigned long long w = d_keys[j];
      rank += (w > k) || (w == k && j < i);
    }
    if (rank < KTOP) f_keys[c * KTOP + rank] = k;
  }
  __syncthreads();

  // ---- stage B: batch top-50 over the 150 per-class entries ----
  if (tid < NCLS * KTOP) {
    const unsigned long long k = f_keys[tid];
    int rank = 0;
    for (int j = 0; j < NCLS * KTOP; ++j) {
      const unsigned long long w = f_keys[j];
      rank += (w > k) || (w == k && j < tid);
    }
    if (rank < KTOP) sel[rank] = tid;
  }
  __syncthreads();

  if (tid < KTOP) {
    const unsigned long long k = f_keys[sel[tid]];
    const float score = __uint_as_float((unsigned int)(k >> 19));
    const int cls = 2 - (int)((k >> 17) & 3);
    const int ind = ((int)(k & 0x1FFFF)) ^ 0x1FFFF;
    const float ys = (float)(ind / Wd);
    const float xs = (float)(ind - (ind / Wd) * Wd);

    const float* rb = regr + (size_t)b * 8 * HWp + ind;
    const float r0 = rb[0 * HWp], r1 = rb[1 * HWp], r2 = rb[2 * HWp], r3 = rb[3 * HWp];
    const float r4 = rb[4 * HWp], r5 = rb[5 * HWp], r6 = rb[6 * HWp], r7 = rb[7 * HWp];

    float tm[9], km[9], tmi[9], kmi[9];
#pragma unroll
    for (int q = 0; q < 9; ++q) { tm[q] = trans_mat[b * 9 + q]; km[q] = K_mat[b * 9 + q]; }
    inv3(tm, tmi);
    inv3(km, kmi);

    const float px = xs + r1, py = ys + r2;
    const float gx = tmi[0] * px + tmi[1] * py + tmi[2];
    const float gy = tmi[3] * px + tmi[4] * py + tmi[5];
    const float gz = tmi[6] * px + tmi[7] * py + tmi[8];
    const float depth = r0 * 16.32f + 28.01f;
    const float qx = gx * depth, qy = gy * depth, qz = gz * depth;
    const float lx = kmi[0] * qx + kmi[1] * qy + kmi[2] * qz;
    float ly = kmi[3] * qx + kmi[4] * qy + kmi[5] * qz;
    const float lz = kmi[6] * qx + kmi[7] * qy + kmi[8] * qz;

    const float d0 = expf(r3) * DIM_REF_C[cls * 3 + 0];
    const float d1 = expf(r4) * DIM_REF_C[cls * 3 + 1];
    const float d2 = expf(r5) * DIM_REF_C[cls * 3 + 2];
    ly += d1 * 0.5f;

    const float ray = atanf(lx / (lz + 1e-7f));
    float alpha = atanf(r6 / (r7 + 1e-7f));
    alpha += (r7 >= 0.0f) ? -PI_F * 0.5f : PI_F * 0.5f;
    const float roty = wrap_pi(alpha + ray);
    alpha = wrap_pi(alpha);

    const float SX[8] = {-0.5f, 0.5f, 0.5f, 0.5f, 0.5f, -0.5f, -0.5f, -0.5f};
    const float SY[8] = {-1.0f, -1.0f, 0.0f, 0.0f, -1.0f, -1.0f, 0.0f, 0.0f};
    const float SZ[8] = {-0.5f, -0.5f, -0.5f, 0.5f, 0.5f, 0.5f, 0.5f, -0.5f};
    const float cr = cosf(roty), sr = sinf(roty);
    float minx = INFINITY, maxx = -INFINITY, miny = INFINITY, maxy = -INFINITY;
#pragma unroll
    for (int j = 0; j < 8; ++j) {
      const float ax = d0 * SX[j], ay = d1 * SY[j], az = d2 * SZ[j];
      const float cx = cr * ax + sr * az + lx;
      const float cy = ay + ly;
      const float cz = -sr * ax + cr * az + lz;
      const float ppx = km[0] * cx + km[1] * cy + km[2] * cz;
      const float ppy = km[3] * cx + km[4] * cy + km[5] * cz;
      const float ppz = km[6] * cx + km[7] * cy + km[8] * cz;
      const float X = ppx / ppz, Y = ppy / ppz;
      minx = fminf(minx, X); maxx = fmaxf(maxx, X);
      miny = fminf(miny, Y); maxy = fmaxf(maxy, Y);
    }
    const float Wi = img_size[b * 2 + 0], Hi = img_size[b * 2 + 1];
    const float xmin = fminf(fmaxf(minx, 0.0f), Wi);
    const float ymin = fminf(fmaxf(miny, 0.0f), Hi);
    const float xmax = fminf(fmaxf(maxx, 0.0f), Wi);
    const float ymax = fminf(fmaxf(maxy, 0.0f), Hi);

    float* o = out + (size_t)(b * KTOP + tid) * 14;
    if (score > 0.25f) {
      o[0] = (float)cls; o[1] = alpha;
      o[2] = xmin; o[3] = ymin; o[4] = xmax; o[5] = ymax;
      o[6] = d1; o[7] = d2; o[8] = d0;   // dims rolled by -1
      o[9] = lx; o[10] = ly; o[11] = lz;
      o[12] = roty; o[13] = score;
    } else {
#pragma unroll
      for (int q = 0; q < 14; ++q) o[q] = 0.0f;
    }
  }
}

// ---------------------------------------------------------------------------

extern "C" void kernel_launch(void* const* d_in, const int* in_sizes, int n_in,
                              void* d_out, int out_size, void* d_ws, size_t ws_size,
                              hipStream_t stream) {
  const float* heat = (const float*)d_in[0];  // [32,3,192,640]
  const float* regr = (const float*)d_in[1];  // [32,8,192,640]
  const float* tmat = (const float*)d_in[2];  // [32,3,3]
  const float* kmat = (const float*)d_in[3];  // [32,3,3]
  const float* isz = (const float*)d_in[4];   // [32,2]

  char* ws = (char*)d_ws;
  float* ssc = (float*)(ws + OFF_SSC);
  int* spi = (int*)(ws + OFF_SPI);
  int* scnt = (int*)(ws + OFF_SCNT);

  scanrank_kernel<<<NPL * NSUB, 256, 0, stream>>>(heat, ssc, spi, scnt);
  decode_kernel<<<NB, 256, 0, stream>>>(heat, ssc, spi, scnt,
                                        regr, tmat, kmat, isz,
                                        (float*)d_out);
}

// Round 6
// 211.351 us; speedup vs baseline: 1.3439x; 1.3439x over previous
//
#include <hip/hip_runtime.h>
#include <math.h>

#define Hd 192
#define Wd 640
#define HWp (Hd * Wd)
#define NCLS 3
#define KTOP 50
#define NB 32
#define NPL (NB * NCLS)      // 96 planes
#define SPR 40               // 16-px strips per row
#define TSTR (Hd * SPR)      // 7680 strips per plane
#define NSUB 6               // sub-blocks per plane
#define SSTR (TSTR / NSUB)   // 1280 strips per sub-block
#define CAPS 512             // per-sub candidate cap (E~98, 29 sigma)
#define CAP 2048             // decode-fallback candidate cap
#define RBK 256              // rank buckets
#define GPR 160              // 4-px groups per row (fallback scanner)
#define GPP (HWp / 4)        // 30720 groups per plane (fallback scanner)
#define NMERGE (NCLS * NSUB * KTOP)  // 900
#define TH_F 0.995f
#define PI_F 3.14159265358979f

// ---- workspace layout (coherence via the single kernel boundary only) ----
#define OFF_SSC 0            // sub_sc: [NPL*NSUB][64] floats = 147456 B
#define OFF_SPI 0x40000      // sub_pi: [NPL*NSUB][64] ints
#define OFF_SCNT 0x80000     // sub_cnt: [NPL*NSUB] ints

__device__ inline float fmax3(float a, float b, float c) {
  return fmaxf(fmaxf(a, b), c);
}

// key = (bits << 32) | ~idx : strict u64 '>' == (value desc, idx asc).
__device__ inline unsigned long long mk_key(unsigned int bits, int idx) {
  return ((unsigned long long)bits << 32) | (unsigned int)~idx;
}

// Monotone bucket over value bits; ~uniform on [0.995, 1.0); clamped outside.
__device__ inline int bucket_of(unsigned int bits) {
  const unsigned int base = __float_as_uint(TH_F);
  if (bits <= base) return 0;
  unsigned int d = (bits - base) >> 9;
  return d > 255u ? 255 : (int)d;
}

// Composed merge key: (score bits)<<19 | (2-cls)<<17 | (idx ^ 0x1FFFF).
// Strict u64 '>' == (score desc, cls asc, idx asc) — the reference's
// flattened-position tie order. idx < 122880 < 2^17.
__device__ inline unsigned long long mk_key19(unsigned int bits, int cls, int idx) {
  return ((unsigned long long)bits << 19) |
         ((unsigned long long)(2 - cls) << 17) |
         (unsigned long long)((idx ^ 0x1FFFF) & 0x1FFFF);
}

// ---------------------------------------------------------------------------
// 16-px row segment, all named fields (registers only — no arrays).
// ---------------------------------------------------------------------------
struct Row16 {
  float4 q0, q1, q2, q3;
  float l, r;
};

__device__ inline Row16 load_row16(const float* __restrict__ rp, int x0, bool valid) {
  Row16 o;
  if (valid) {
    o.q0 = *(const float4*)(rp);
    o.q1 = *(const float4*)(rp + 4);
    o.q2 = *(const float4*)(rp + 8);
    o.q3 = *(const float4*)(rp + 12);
    o.l = (x0 > 0) ? rp[-1] : -INFINITY;
    o.r = (x0 + 16 < Wd) ? rp[16] : -INFINITY;
  } else {
    o.q0.x = o.q0.y = o.q0.z = o.q0.w = -INFINITY;
    o.q1 = o.q0; o.q2 = o.q0; o.q3 = o.q0;
    o.l = -INFINITY; o.r = -INFINITY;
  }
  return o;
}

__device__ inline float4 max3v(const float4 a, const float4 b, const float4 c) {
  float4 o;
  o.x = fmax3(a.x, b.x, c.x);
  o.y = fmax3(a.y, b.y, c.y);
  o.z = fmax3(a.z, b.z, c.z);
  o.w = fmax3(a.w, b.w, c.w);
  return o;
}

// Visit every >=TH 8-neighborhood peak in one 16-px strip.
template <typename F>
__device__ inline void strip_peaks(const float* __restrict__ hp, int strip, F&& f) {
  const int y = strip / SPR;
  const int x0 = (strip - y * SPR) * 16;
  const float* pm = hp + y * Wd + x0;
  const Row16 m = load_row16(pm, x0, true);
  const Row16 t = load_row16(pm - Wd, x0, y > 0);
  const Row16 b = load_row16(pm + Wd, x0, y < Hd - 1);
  const float cl = fmax3(t.l, m.l, b.l);
  const float cr = fmax3(t.r, m.r, b.r);
  const float4 c0 = max3v(t.q0, m.q0, b.q0);
  const float4 c1 = max3v(t.q1, m.q1, b.q1);
  const float4 c2 = max3v(t.q2, m.q2, b.q2);
  const float4 c3 = max3v(t.q3, m.q3, b.q3);
  const int base = y * Wd + x0;
#define EMIT(V, W0, W1, W2, J)                                       \
  if ((V) >= TH_F && (V) == fmax3((W0), (W1), (W2)))                 \
    f(__float_as_uint(V), base + (J));
  EMIT(m.q0.x, cl,   c0.x, c0.y, 0)
  EMIT(m.q0.y, c0.x, c0.y, c0.z, 1)
  EMIT(m.q0.z, c0.y, c0.z, c0.w, 2)
  EMIT(m.q0.w, c0.z, c0.w, c1.x, 3)
  EMIT(m.q1.x, c0.w, c1.x, c1.y, 4)
  EMIT(m.q1.y, c1.x, c1.y, c1.z, 5)
  EMIT(m.q1.z, c1.y, c1.z, c1.w, 6)
  EMIT(m.q1.w, c1.z, c1.w, c2.x, 7)
  EMIT(m.q2.x, c1.w, c2.x, c2.y, 8)
  EMIT(m.q2.y, c2.x, c2.y, c2.z, 9)
  EMIT(m.q2.z, c2.y, c2.z, c2.w, 10)
  EMIT(m.q2.w, c2.z, c2.w, c3.x, 11)
  EMIT(m.q3.x, c2.w, c3.x, c3.y, 12)
  EMIT(m.q3.y, c3.x, c3.y, c3.z, 13)
  EMIT(m.q3.z, c3.y, c3.z, c3.w, 14)
  EMIT(m.q3.w, c3.z, c3.w, cr,   15)
#undef EMIT
}

// ---------------------------------------------------------------------------
// Whole-plane 4-px-group peak scanner (decode's exact-rescan fallback only;
// visits ALL peaks, no threshold).
// ---------------------------------------------------------------------------
template <typename F>
__device__ inline void peaks_in_group(const float* __restrict__ p, int g, F&& f) {
  const int y = g / GPR;
  const int x0 = (g - y * GPR) * 4;
  const float* rm = p + y * Wd + x0;
  const float4 mq = *(const float4*)rm;
  const float ml = (x0 > 0) ? rm[-1] : -INFINITY;
  const float mr = (x0 + 4 < Wd) ? rm[4] : -INFINITY;
  float4 tq; float tl, tr;
  if (y > 0) {
    const float* rt = rm - Wd;
    tq = *(const float4*)rt;
    tl = (x0 > 0) ? rt[-1] : -INFINITY;
    tr = (x0 + 4 < Wd) ? rt[4] : -INFINITY;
  } else {
    tq.x = tq.y = tq.z = tq.w = -INFINITY; tl = -INFINITY; tr = -INFINITY;
  }
  float4 bq; float bl, br;
  if (y < Hd - 1) {
    const float* rb = rm + Wd;
    bq = *(const float4*)rb;
    bl = (x0 > 0) ? rb[-1] : -INFINITY;
    br = (x0 + 4 < Wd) ? rb[4] : -INFINITY;
  } else {
    bq.x = bq.y = bq.z = bq.w = -INFINITY; bl = -INFINITY; br = -INFINITY;
  }
  const float c0 = fmax3(tl, ml, bl);
  const float c1 = fmax3(tq.x, mq.x, bq.x);
  const float c2 = fmax3(tq.y, mq.y, bq.y);
  const float c3 = fmax3(tq.z, mq.z, bq.z);
  const float c4 = fmax3(tq.w, mq.w, bq.w);
  const float c5 = fmax3(tr, mr, br);
  const int base = y * Wd + x0;
  if (mq.x == fmax3(c0, c1, c2)) f(__float_as_uint(mq.x), base + 0);
  if (mq.y == fmax3(c1, c2, c3)) f(__float_as_uint(mq.y), base + 1);
  if (mq.z == fmax3(c2, c3, c4)) f(__float_as_uint(mq.z), base + 2);
  if (mq.w == fmax3(c3, c4, c5)) f(__float_as_uint(mq.w), base + 3);
}

template <typename F>
__device__ inline void for_each_peak_plane(const float* __restrict__ p, int tid,
                                           int nth, F&& f) {
  for (int g = tid; g < GPP; g += nth) peaks_in_group(p, g, f);
}

__device__ inline void inv3(const float* m, float* o) {
  float a = m[0], b = m[1], c = m[2];
  float d = m[3], e = m[4], f = m[5];
  float g = m[6], h = m[7], i = m[8];
  float A = e * i - f * h;
  float B = -(d * i - f * g);
  float C = d * h - e * g;
  float det = a * A + b * B + c * C;
  float id = 1.0f / det;
  o[0] = A * id;            o[1] = -(b * i - c * h) * id; o[2] = (b * f - c * e) * id;
  o[3] = B * id;            o[4] = (a * i - c * g) * id;  o[5] = -(a * f - c * d) * id;
  o[6] = C * id;            o[7] = -(a * h - b * g) * id; o[8] = (a * e - b * d) * id;
}

__device__ inline float wrap_pi(float a) {
  if (a > PI_F) return a - 2.0f * PI_F;
  if (a < -PI_F) return a + 2.0f * PI_F;
  return a;
}

__constant__ float DIM_REF_C[9] = {3.88f, 1.63f, 1.53f,
                                   0.84f, 1.76f, 0.66f,
                                   1.78f, 1.52f, 1.78f};

// ---------------------------------------------------------------------------
// Kernel 1: fused scan+rank. 576 blocks (plane-sixths) x 256 threads, 5
// strips/thread. Candidates collected in LDS, counting-sort ranked in-block,
// only the sub-top-50 hits HBM. No cross-block traffic of any kind.
// (Unchanged from R5 — its dispatch didn't make top-5; decode was the hotspot.)
// ---------------------------------------------------------------------------
__global__ __launch_bounds__(256) void scanrank_kernel(
    const float* __restrict__ heat,
    float* __restrict__ ssc,    // [NPL*NSUB][64]
    int* __restrict__ spi,      // [NPL*NSUB][64]
    int* __restrict__ scnt) {   // [NPL*NSUB]
  const int blk = blockIdx.x;
  const int tid = threadIdx.x;
  const int plane = blk / NSUB;
  const int sub = blk - plane * NSUB;
  const float* hp = heat + (size_t)plane * HWp;
  const int sbase = sub * SSTR;

  __shared__ unsigned long long s_key[CAPS];   // 4 KB raw candidates
  __shared__ unsigned long long c_key[CAPS];   // 4 KB grouped (aliases hist)
  __shared__ int cnt[RBK], suf[RBK], cur[RBK];
  __shared__ int s_n, s_B, s_above, s_T;

  if (tid == 0) s_n = 0;
  __syncthreads();

  // ---- collect >=TH peaks over this block's 1280 strips ----
  for (int it = 0; it < SSTR / 256; ++it) {
    const int strip = sbase + it * 256 + tid;
    strip_peaks(hp, strip, [&](unsigned int bits, int idx) {
      int slot = atomicAdd(&s_n, 1);
      if (slot < CAPS) s_key[slot] = mk_key(bits, idx);
    });
  }
  __syncthreads();
  int n = s_n;

  if (n > CAPS) {
    // Overflow (29-sigma event): raise the threshold via a two-level
    // histogram over [TH, 1.0) and recollect. Exact for the top-50.
    unsigned int* hist = (unsigned int*)c_key;   // 1024 u32 = 4 KB
    const unsigned int THB = __float_as_uint(TH_F);
    for (int i = tid; i < 1024; i += 256) hist[i] = 0;
    __syncthreads();
    for (int it = 0; it < SSTR / 256; ++it) {
      const int strip = sbase + it * 256 + tid;
      strip_peaks(hp, strip, [&](unsigned int bits, int idx) {
        atomicAdd(&hist[(bits - THB) >> 7], 1u);   // <= 655
      });
    }
    __syncthreads();
    if (tid == 0) {
      int acc = 0, res = 0, above = 0;
      for (int q = 655; q >= 0; --q) {
        int cc = (int)hist[q];
        if (acc + cc >= KTOP) { res = q; above = acc; break; }
        acc += cc;
      }
      s_B = res; s_above = above;
    }
    __syncthreads();
    const int Bc = s_B;
    for (int i = tid; i < 1024; i += 256) hist[i] = 0;
    __syncthreads();
    for (int it = 0; it < SSTR / 256; ++it) {
      const int strip = sbase + it * 256 + tid;
      strip_peaks(hp, strip, [&](unsigned int bits, int idx) {
        if ((int)((bits - THB) >> 7) == Bc)
          atomicAdd(&hist[(bits - THB) & 127], 1u);
      });
    }
    __syncthreads();
    if (tid == 0) {
      int acc = s_above, S = 0;
      for (int sb = 127; sb >= 0; --sb) {
        int cc = (int)hist[sb];
        if (acc + cc >= KTOP) { S = sb; break; }
        acc += cc;
      }
      s_T = (int)(THB + ((unsigned int)Bc << 7) + (unsigned int)S);
      s_n = 0;
    }
    __syncthreads();
    const unsigned int T = (unsigned int)s_T;
    for (int it = 0; it < SSTR / 256; ++it) {
      const int strip = sbase + it * 256 + tid;
      strip_peaks(hp, strip, [&](unsigned int bits, int idx) {
        if (bits >= T) {
          int slot = atomicAdd(&s_n, 1);
          if (slot < CAPS) s_key[slot] = mk_key(bits, idx);
        }
      });
    }
    __syncthreads();
    n = s_n < CAPS ? s_n : CAPS;
  }

  // ---- O(n) counting-sort rank: (value desc, idx asc). ----
  cnt[tid] = 0;
  cur[tid] = 0;
  __syncthreads();
  for (int i = tid; i < n; i += 256)
    atomicAdd(&cnt[bucket_of((unsigned int)(s_key[i] >> 32))], 1);
  __syncthreads();
  suf[tid] = cnt[tid];
  __syncthreads();
#pragma unroll
  for (int d = 1; d < RBK; d <<= 1) {
    const int v = (tid + d < RBK) ? suf[tid + d] : 0;
    __syncthreads();
    suf[tid] += v;
    __syncthreads();
  }
  {
    const int excl = suf[tid] - cnt[tid];   // keys in buckets > tid
    __syncthreads();
    suf[tid] = excl;
  }
  __syncthreads();
  for (int i = tid; i < n; i += 256) {
    const unsigned long long k = s_key[i];
    const int bq = bucket_of((unsigned int)(k >> 32));
    const int slot = suf[bq] + atomicAdd(&cur[bq], 1);
    c_key[slot] = k;
  }
  __syncthreads();
  float* psc = ssc + blk * 64;
  int* ppi = spi + blk * 64;
  for (int i = tid; i < n; i += 256) {
    const unsigned long long k = c_key[i];
    const int bq = bucket_of((unsigned int)(k >> 32));
    const int st = suf[bq];
    const int nb = cnt[bq];
    int rank = st;
    for (int tt = st; tt < st + nb; ++tt) rank += (c_key[tt] > k);
    if (rank < KTOP) {
      psc[rank] = __uint_as_float((unsigned int)(k >> 32));
      ppi[rank] = (int)~((unsigned int)k);
    }
  }
  for (int s2 = n + tid; s2 < KTOP; s2 += 256) {
    psc[s2] = 0.0f;
    ppi[s2] = 0;
  }
  if (tid == 0) scnt[blk] = n;
}

// ---------------------------------------------------------------------------
// Kernel 2: merge + top-50 + 3D decode. 32 blocks x 256 threads.
// The batch top-50 == top-50 of the 900 merged composed keys (score desc,
// cls asc, idx asc), ranked via bucketed counting-sort — NO long
// dependent-branch LDS loops (R5's 88 µs lesson: 300-iter load->branch
// chains run at ds_read LATENCY, ~120 cyc each).
// ---------------------------------------------------------------------------
__global__ __launch_bounds__(256) void decode_kernel(
    const float* __restrict__ heat,
    const float* __restrict__ ssc,
    const int* __restrict__ spi,
    const int* __restrict__ scnt,
    const float* __restrict__ regr,      // [B][8][HWp]
    const float* __restrict__ trans_mat, // [B][3][3]
    const float* __restrict__ K_mat,     // [B][3][3]
    const float* __restrict__ img_size,  // [B][2]
    float* __restrict__ out) {           // [B*50][14]
  const int b = blockIdx.x;
  const int tid = threadIdx.x;

  __shared__ unsigned long long d_keys[NMERGE];     // 7.2 KB merged keys
  __shared__ unsigned long long g_keys[NMERGE];     // 7.2 KB bucket-grouped
  __shared__ int cnt[RBK], suf[RBK], cur[RBK];
  __shared__ int sel[KTOP];
  __shared__ int s_ctl[NCLS * NSUB];
  __shared__ int s_ct[NCLS];
  // fallback scratch (exact whole-plane rescan; never fires on this data)
  __shared__ unsigned long long s_key[CAP];         // 16 KB
  __shared__ unsigned long long c_key[CAP];         // 16 KB (hist alias)
  __shared__ int s_fbB, s_fbAbove, s_fbT, s_fbCnt;

  // true per-class >=TH candidate totals (parallel load, then tiny reduce)
  if (tid < NCLS * NSUB) s_ctl[tid] = scnt[b * NCLS * NSUB + tid];
  __syncthreads();
  if (tid < NCLS) {
    int t = 0;
#pragma unroll
    for (int s = 0; s < NSUB; ++s) t += s_ctl[tid * NSUB + s];
    s_ct[tid] = t;
  }
  __syncthreads();

  // build merged composed keys from the 18 sub-top-50 lists
  for (int i = tid; i < NMERGE; i += 256) {
    const int c = i / (NSUB * KTOP);
    const int rem = i - c * (NSUB * KTOP);
    const int s = rem / KTOP;
    const int k2 = rem - s * KTOP;
    const int sb = (b * NCLS + c) * NSUB + s;
    const float v = ssc[sb * 64 + k2];
    const int idx = spi[sb * 64 + k2];
    d_keys[i] = mk_key19(__float_as_uint(v), c, idx);
  }
  __syncthreads();

  // per-class exactness fallback: plane has <50 peaks >= TH -> exact rescan
  for (int c = 0; c < NCLS; ++c) {
    if (s_ct[c] < KTOP) {
      const float* hp = heat + (size_t)(b * NCLS + c) * HWp;
      unsigned int* fb_hist = (unsigned int*)c_key;
      for (int i = tid; i < 1024; i += 256) fb_hist[i] = 0;
      __syncthreads();
      for_each_peak_plane(hp, tid, 256, [&](unsigned int bits, int idx) {
        unsigned int bkt = bits >> 20; if (bkt > 1023u) bkt = 1023u;
        atomicAdd(&fb_hist[bkt], 1u);
      });
      __syncthreads();
      if (tid == 0) {
        int acc = 0, Bs = -1;
        for (int bkt = 1023; bkt >= 0; --bkt) {
          int cc = (int)fb_hist[bkt];
          if (acc + cc >= KTOP) { Bs = bkt; s_fbAbove = acc; break; }
          acc += cc;
        }
        s_fbB = Bs;
        if (Bs < 0) s_fbAbove = acc;
      }
      __syncthreads();
      const int Bs = s_fbB;
      unsigned int T;
      if (Bs < 0) {
        T = 0;  // fewer than 50 peaks total: take them all
      } else {
        for (int i = tid; i < 1024; i += 256) fb_hist[i] = 0;
        __syncthreads();
        for_each_peak_plane(hp, tid, 256, [&](unsigned int bits, int idx) {
          unsigned int bkt = bits >> 20; if (bkt > 1023u) bkt = 1023u;
          if ((int)bkt == Bs) atomicAdd(&fb_hist[(bits >> 10) & 1023], 1u);
        });
        __syncthreads();
        if (tid == 0) {
          int acc = s_fbAbove, Ss = 0;
          for (int sb = 1023; sb >= 0; --sb) {
            int cc = (int)fb_hist[sb];
            if (acc + cc >= KTOP) { Ss = sb; break; }
            acc += cc;
          }
          s_fbT = (int)(((unsigned int)Bs << 20) | ((unsigned int)Ss << 10));
        }
        __syncthreads();
        T = (unsigned int)s_fbT;
      }
      if (tid == 0) s_fbCnt = 0;
      __syncthreads();
      for_each_peak_plane(hp, tid, 256, [&](unsigned int bits, int idx) {
        if (bits >= T) {
          int slot = atomicAdd(&s_fbCnt, 1);
          if (slot < CAP) s_key[slot] = mk_key(bits, idx);
        }
      });
      __syncthreads();
      const int M = s_fbCnt < CAP ? s_fbCnt : CAP;
      // rank M keys, write class-c top-50 into its d_keys slice
      cnt[tid] = 0; cur[tid] = 0;
      __syncthreads();
      for (int i = tid; i < M; i += 256)
        atomicAdd(&cnt[bucket_of((unsigned int)(s_key[i] >> 32))], 1);
      __syncthreads();
      suf[tid] = cnt[tid];
      __syncthreads();
#pragma unroll
      for (int d = 1; d < RBK; d <<= 1) {
        const int v = (tid + d < RBK) ? suf[tid + d] : 0;
        __syncthreads();
        suf[tid] += v;
        __syncthreads();
      }
      {
        const int excl = suf[tid] - cnt[tid];
        __syncthreads();
        suf[tid] = excl;
      }
      __syncthreads();
      for (int i = tid; i < M; i += 256) {
        const unsigned long long k = s_key[i];
        const int bq = bucket_of((unsigned int)(k >> 32));
        const int slot = suf[bq] + atomicAdd(&cur[bq], 1);
        c_key[slot] = k;
      }
      __syncthreads();
      for (int i = tid; i < NSUB * KTOP; i += 256)   // clear class slice
        d_keys[c * (NSUB * KTOP) + i] = mk_key19(0u, c, 0);
      __syncthreads();
      for (int i = tid; i < M; i += 256) {
        const unsigned long long k = c_key[i];
        const int bq = bucket_of((unsigned int)(k >> 32));
        const int st = suf[bq];
        const int nb = cnt[bq];
        int rank = st;
        for (int tt = st; tt < st + nb; ++tt) rank += (c_key[tt] > k);
        if (rank < KTOP)
          d_keys[c * (NSUB * KTOP) + rank] =
              mk_key19((unsigned int)(k >> 32), c, (int)~((unsigned int)k));
      }
      __syncthreads();
    }
  }

  // ---- top-50 of the 900 composed keys via bucketed counting-sort ----
  cnt[tid] = 0;
  cur[tid] = 0;
  __syncthreads();
  for (int i = tid; i < NMERGE; i += 256)
    atomicAdd(&cnt[bucket_of((unsigned int)(d_keys[i] >> 19))], 1);
  __syncthreads();
  suf[tid] = cnt[tid];
  __syncthreads();
#pragma unroll
  for (int d = 1; d < RBK; d <<= 1) {
    const int v = (tid + d < RBK) ? suf[tid + d] : 0;
    __syncthreads();
    suf[tid] += v;
    __syncthreads();
  }
  {
    const int excl = suf[tid] - cnt[tid];   // keys in buckets > tid
    __syncthreads();
    suf[tid] = excl;
  }
  __syncthreads();
  for (int i = tid; i < NMERGE; i += 256) {
    const unsigned long long k = d_keys[i];
    const int bq = bucket_of((unsigned int)(k >> 19));
    const int slot = suf[bq] + atomicAdd(&cur[bq], 1);
    g_keys[slot] = k;
  }
  __syncthreads();
  for (int i = tid; i < NMERGE; i += 256) {
    const unsigned long long k = g_keys[i];
    const int bq = bucket_of((unsigned int)(k >> 19));
    const int st = suf[bq];
    if (st >= KTOP) continue;   // whole bucket below top-50 (prunes padding)
    const int nb = cnt[bq];
    int rank = st;
    for (int tt = st; tt < st + nb; ++tt) rank += (g_keys[tt] > k);
    if (rank < KTOP) sel[rank] = i;
  }
  __syncthreads();

  if (tid < KTOP) {
    const unsigned long long k = g_keys[sel[tid]];
    const float score = __uint_as_float((unsigned int)(k >> 19));
    const int cls = 2 - (int)((k >> 17) & 3);
    const int ind = ((int)(k & 0x1FFFF)) ^ 0x1FFFF;
    const float ys = (float)(ind / Wd);
    const float xs = (float)(ind - (ind / Wd) * Wd);

    const float* rb = regr + (size_t)b * 8 * HWp + ind;
    const float r0 = rb[0 * HWp], r1 = rb[1 * HWp], r2 = rb[2 * HWp], r3 = rb[3 * HWp];
    const float r4 = rb[4 * HWp], r5 = rb[5 * HWp], r6 = rb[6 * HWp], r7 = rb[7 * HWp];

    float tm[9], km[9], tmi[9], kmi[9];
#pragma unroll
    for (int q = 0; q < 9; ++q) { tm[q] = trans_mat[b * 9 + q]; km[q] = K_mat[b * 9 + q]; }
    inv3(tm, tmi);
    inv3(km, kmi);

    const float px = xs + r1, py = ys + r2;
    const float gx = tmi[0] * px + tmi[1] * py + tmi[2];
    const float gy = tmi[3] * px + tmi[4] * py + tmi[5];
    const float gz = tmi[6] * px + tmi[7] * py + tmi[8];
    const float depth = r0 * 16.32f + 28.01f;
    const float qx = gx * depth, qy = gy * depth, qz = gz * depth;
    const float lx = kmi[0] * qx + kmi[1] * qy + kmi[2] * qz;
    float ly = kmi[3] * qx + kmi[4] * qy + kmi[5] * qz;
    const float lz = kmi[6] * qx + kmi[7] * qy + kmi[8] * qz;

    const float d0 = expf(r3) * DIM_REF_C[cls * 3 + 0];
    const float d1 = expf(r4) * DIM_REF_C[cls * 3 + 1];
    const float d2 = expf(r5) * DIM_REF_C[cls * 3 + 2];
    ly += d1 * 0.5f;

    const float ray = atanf(lx / (lz + 1e-7f));
    float alpha = atanf(r6 / (r7 + 1e-7f));
    alpha += (r7 >= 0.0f) ? -PI_F * 0.5f : PI_F * 0.5f;
    const float roty = wrap_pi(alpha + ray);
    alpha = wrap_pi(alpha);

    const float SX[8] = {-0.5f, 0.5f, 0.5f, 0.5f, 0.5f, -0.5f, -0.5f, -0.5f};
    const float SY[8] = {-1.0f, -1.0f, 0.0f, 0.0f, -1.0f, -1.0f, 0.0f, 0.0f};
    const float SZ[8] = {-0.5f, -0.5f, -0.5f, 0.5f, 0.5f, 0.5f, 0.5f, -0.5f};
    const float cr = cosf(roty), sr = sinf(roty);
    float minx = INFINITY, maxx = -INFINITY, miny = INFINITY, maxy = -INFINITY;
#pragma unroll
    for (int j = 0; j < 8; ++j) {
      const float ax = d0 * SX[j], ay = d1 * SY[j], az = d2 * SZ[j];
      const float cx = cr * ax + sr * az + lx;
      const float cy = ay + ly;
      const float cz = -sr * ax + cr * az + lz;
      const float ppx = km[0] * cx + km[1] * cy + km[2] * cz;
      const float ppy = km[3] * cx + km[4] * cy + km[5] * cz;
      const float ppz = km[6] * cx + km[7] * cy + km[8] * cz;
      const float X = ppx / ppz, Y = ppy / ppz;
      minx = fminf(minx, X); maxx = fmaxf(maxx, X);
      miny = fminf(miny, Y); maxy = fmaxf(maxy, Y);
    }
    const float Wi = img_size[b * 2 + 0], Hi = img_size[b * 2 + 1];
    const float xmin = fminf(fmaxf(minx, 0.0f), Wi);
    const float ymin = fminf(fmaxf(miny, 0.0f), Hi);
    const float xmax = fminf(fmaxf(maxx, 0.0f), Wi);
    const float ymax = fminf(fmaxf(maxy, 0.0f), Hi);

    float* o = out + (size_t)(b * KTOP + tid) * 14;
    if (score > 0.25f) {
      o[0] = (float)cls; o[1] = alpha;
      o[2] = xmin; o[3] = ymin; o[4] = xmax; o[5] = ymax;
      o[6] = d1; o[7] = d2; o[8] = d0;   // dims rolled by -1
      o[9] = lx; o[10] = ly; o[11] = lz;
      o[12] = roty; o[13] = score;
    } else {
#pragma unroll
      for (int q = 0; q < 14; ++q) o[q] = 0.0f;
    }
  }
}

// ---------------------------------------------------------------------------

extern "C" void kernel_launch(void* const* d_in, const int* in_sizes, int n_in,
                              void* d_out, int out_size, void* d_ws, size_t ws_size,
                              hipStream_t stream) {
  const float* heat = (const float*)d_in[0];  // [32,3,192,640]
  const float* regr = (const float*)d_in[1];  // [32,8,192,640]
  const float* tmat = (const float*)d_in[2];  // [32,3,3]
  const float* kmat = (const float*)d_in[3];  // [32,3,3]
  const float* isz = (const float*)d_in[4];   // [32,2]

  char* ws = (char*)d_ws;
  float* ssc = (float*)(ws + OFF_SSC);
  int* spi = (int*)(ws + OFF_SPI);
  int* scnt = (int*)(ws + OFF_SCNT);

  scanrank_kernel<<<NPL * NSUB, 256, 0, stream>>>(heat, ssc, spi, scnt);
  decode_kernel<<<NB, 256, 0, stream>>>(heat, ssc, spi, scnt,
                                        regr, tmat, kmat, isz,
                                        (float*)d_out);
}

// Round 7
// 200.727 us; speedup vs baseline: 1.4150x; 1.0529x over previous
//
#include <hip/hip_runtime.h>
#include <math.h>

#define Hd 192
#define Wd 640
#define HWp (Hd * Wd)
#define NCLS 3
#define KTOP 50
#define NB 32
#define NPL (NB * NCLS)      // 96 planes
#define NSUB 8               // row-bands per plane (24 rows each)
#define BROWS 24             // rows per band
#define NCOL 40              // 16-px columns per row
#define NACT (NCOL * 6)      // 240 active threads (6 row-groups x 4 rows)
#define CAPS 512             // per-band candidate cap (E~75, >30 sigma)
#define CAP 2048             // decode-fallback candidate cap
#define RBK 256              // rank buckets
#define GPR 160              // 4-px groups per row (fallback scanner)
#define GPP (HWp / 4)        // 30720 groups per plane (fallback scanner)
#define NMERGE (NCLS * NSUB * KTOP)  // 1200
#define TH_F 0.995f
#define PI_F 3.14159265358979f

// ---- workspace layout (coherence via the single kernel boundary only) ----
#define OFF_SSC 0            // sub_sc: [NPL*NSUB][64] floats = 196608 B
#define OFF_SPI 0x40000      // sub_pi: [NPL*NSUB][64] ints
#define OFF_SCNT 0x80000     // sub_cnt: [NPL*NSUB] ints

__device__ inline float fmax3(float a, float b, float c) {
  return fmaxf(fmaxf(a, b), c);
}

// key = (bits << 32) | ~idx : strict u64 '>' == (value desc, idx asc).
__device__ inline unsigned long long mk_key(unsigned int bits, int idx) {
  return ((unsigned long long)bits << 32) | (unsigned int)~idx;
}

// Monotone bucket over value bits; ~uniform on [0.995, 1.0); clamped outside.
__device__ inline int bucket_of(unsigned int bits) {
  const unsigned int base = __float_as_uint(TH_F);
  if (bits <= base) return 0;
  unsigned int d = (bits - base) >> 9;
  return d > 255u ? 255 : (int)d;
}

// Composed merge key: (score bits)<<19 | (2-cls)<<17 | (idx ^ 0x1FFFF).
// Strict u64 '>' == (score desc, cls asc, idx asc) — the reference's
// flattened-position tie order. idx < 122880 < 2^17.
__device__ inline unsigned long long mk_key19(unsigned int bits, int cls, int idx) {
  return ((unsigned long long)bits << 19) |
         ((unsigned long long)(2 - cls) << 17) |
         (unsigned long long)((idx ^ 0x1FFFF) & 0x1FFFF);
}

// ---------------------------------------------------------------------------
// 16-px row segment, all named fields (registers only — no arrays).
// ---------------------------------------------------------------------------
struct Row16 {
  float4 q0, q1, q2, q3;
  float l, r;
};

__device__ inline Row16 load_row16(const float* __restrict__ rp, int x0, bool valid) {
  Row16 o;
  if (valid) {
    o.q0 = *(const float4*)(rp);
    o.q1 = *(const float4*)(rp + 4);
    o.q2 = *(const float4*)(rp + 8);
    o.q3 = *(const float4*)(rp + 12);
    o.l = (x0 > 0) ? rp[-1] : -INFINITY;
    o.r = (x0 + 16 < Wd) ? rp[16] : -INFINITY;
  } else {
    o.q0.x = o.q0.y = o.q0.z = o.q0.w = -INFINITY;
    o.q1 = o.q0; o.q2 = o.q0; o.q3 = o.q0;
    o.l = -INFINITY; o.r = -INFINITY;
  }
  return o;
}

__device__ inline float4 max3v(const float4 a, const float4 b, const float4 c) {
  float4 o;
  o.x = fmax3(a.x, b.x, c.x);
  o.y = fmax3(a.y, b.y, c.y);
  o.z = fmax3(a.z, b.z, c.z);
  o.w = fmax3(a.w, b.w, c.w);
  return o;
}

// ---------------------------------------------------------------------------
// Band scan with register-rolling rows: each active thread owns a 16-px
// column x 4 consecutive rows; 6 row-loads feed 4 strips (vs 12 for the old
// one-strip-per-thread layout — the 3x redundant row traffic was the R6
// scanrank cost theory). Calls f(bits, idx) per >=TH 8-neighborhood peak.
// ---------------------------------------------------------------------------
template <typename F>
__device__ inline void band_scan(const float* __restrict__ hp, int band,
                                 int tid, F&& f) {
  if (tid >= NACT) return;
  const int c = tid % NCOL;
  const int rg = tid / NCOL;          // 0..5
  const int r0 = band * BROWS + rg * 4;
  const int x0 = c * 16;
  const float* colp = hp + x0;

  Row16 rt = load_row16(colp + (long)(r0 - 1) * Wd, x0, r0 > 0);
  Row16 rm = load_row16(colp + (long)r0 * Wd, x0, true);
#pragma unroll
  for (int j = 0; j < 4; ++j) {
    const int y = r0 + j;
    const Row16 rb = load_row16(colp + (long)(y + 1) * Wd, x0, y + 1 < Hd);

    const float cl = fmax3(rt.l, rm.l, rb.l);
    const float cr = fmax3(rt.r, rm.r, rb.r);
    const float4 c0 = max3v(rt.q0, rm.q0, rb.q0);
    const float4 c1 = max3v(rt.q1, rm.q1, rb.q1);
    const float4 c2 = max3v(rt.q2, rm.q2, rb.q2);
    const float4 c3 = max3v(rt.q3, rm.q3, rb.q3);
    const int base = y * Wd + x0;
#define EMIT(V, W0, W1, W2, J)                                       \
    if ((V) >= TH_F && (V) == fmax3((W0), (W1), (W2)))               \
      f(__float_as_uint(V), base + (J));
    EMIT(rm.q0.x, cl,   c0.x, c0.y, 0)
    EMIT(rm.q0.y, c0.x, c0.y, c0.z, 1)
    EMIT(rm.q0.z, c0.y, c0.z, c0.w, 2)
    EMIT(rm.q0.w, c0.z, c0.w, c1.x, 3)
    EMIT(rm.q1.x, c0.w, c1.x, c1.y, 4)
    EMIT(rm.q1.y, c1.x, c1.y, c1.z, 5)
    EMIT(rm.q1.z, c1.y, c1.z, c1.w, 6)
    EMIT(rm.q1.w, c1.z, c1.w, c2.x, 7)
    EMIT(rm.q2.x, c1.w, c2.x, c2.y, 8)
    EMIT(rm.q2.y, c2.x, c2.y, c2.z, 9)
    EMIT(rm.q2.z, c2.y, c2.z, c2.w, 10)
    EMIT(rm.q2.w, c2.z, c2.w, c3.x, 11)
    EMIT(rm.q3.x, c2.w, c3.x, c3.y, 12)
    EMIT(rm.q3.y, c3.x, c3.y, c3.z, 13)
    EMIT(rm.q3.z, c3.y, c3.z, c3.w, 14)
    EMIT(rm.q3.w, c3.z, c3.w, cr,   15)
#undef EMIT
    rt = rm;
    rm = rb;
  }
}

// ---------------------------------------------------------------------------
// Whole-plane 4-px-group peak scanner (decode's exact-rescan fallback only;
// visits ALL peaks, no threshold).
// ---------------------------------------------------------------------------
template <typename F>
__device__ inline void peaks_in_group(const float* __restrict__ p, int g, F&& f) {
  const int y = g / GPR;
  const int x0 = (g - y * GPR) * 4;
  const float* rm = p + y * Wd + x0;
  const float4 mq = *(const float4*)rm;
  const float ml = (x0 > 0) ? rm[-1] : -INFINITY;
  const float mr = (x0 + 4 < Wd) ? rm[4] : -INFINITY;
  float4 tq; float tl, tr;
  if (y > 0) {
    const float* rt = rm - Wd;
    tq = *(const float4*)rt;
    tl = (x0 > 0) ? rt[-1] : -INFINITY;
    tr = (x0 + 4 < Wd) ? rt[4] : -INFINITY;
  } else {
    tq.x = tq.y = tq.z = tq.w = -INFINITY; tl = -INFINITY; tr = -INFINITY;
  }
  float4 bq; float bl, br;
  if (y < Hd - 1) {
    const float* rb = rm + Wd;
    bq = *(const float4*)rb;
    bl = (x0 > 0) ? rb[-1] : -INFINITY;
    br = (x0 + 4 < Wd) ? rb[4] : -INFINITY;
  } else {
    bq.x = bq.y = bq.z = bq.w = -INFINITY; bl = -INFINITY; br = -INFINITY;
  }
  const float c0 = fmax3(tl, ml, bl);
  const float c1 = fmax3(tq.x, mq.x, bq.x);
  const float c2 = fmax3(tq.y, mq.y, bq.y);
  const float c3 = fmax3(tq.z, mq.z, bq.z);
  const float c4 = fmax3(tq.w, mq.w, bq.w);
  const float c5 = fmax3(tr, mr, br);
  const int base = y * Wd + x0;
  if (mq.x == fmax3(c0, c1, c2)) f(__float_as_uint(mq.x), base + 0);
  if (mq.y == fmax3(c1, c2, c3)) f(__float_as_uint(mq.y), base + 1);
  if (mq.z == fmax3(c2, c3, c4)) f(__float_as_uint(mq.z), base + 2);
  if (mq.w == fmax3(c3, c4, c5)) f(__float_as_uint(mq.w), base + 3);
}

template <typename F>
__device__ inline void for_each_peak_plane(const float* __restrict__ p, int tid,
                                           int nth, F&& f) {
  for (int g = tid; g < GPP; g += nth) peaks_in_group(p, g, f);
}

__device__ inline void inv3(const float* m, float* o) {
  float a = m[0], b = m[1], c = m[2];
  float d = m[3], e = m[4], f = m[5];
  float g = m[6], h = m[7], i = m[8];
  float A = e * i - f * h;
  float B = -(d * i - f * g);
  float C = d * h - e * g;
  float det = a * A + b * B + c * C;
  float id = 1.0f / det;
  o[0] = A * id;            o[1] = -(b * i - c * h) * id; o[2] = (b * f - c * e) * id;
  o[3] = B * id;            o[4] = (a * i - c * g) * id;  o[5] = -(a * f - c * d) * id;
  o[6] = C * id;            o[7] = -(a * h - b * g) * id; o[8] = (a * e - b * d) * id;
}

__device__ inline float wrap_pi(float a) {
  if (a > PI_F) return a - 2.0f * PI_F;
  if (a < -PI_F) return a + 2.0f * PI_F;
  return a;
}

__constant__ float DIM_REF_C[9] = {3.88f, 1.63f, 1.53f,
                                   0.84f, 1.76f, 0.66f,
                                   1.78f, 1.52f, 1.78f};

// ---------------------------------------------------------------------------
// Kernel 1: fused scan+rank. 768 blocks (plane x 8 bands) x 256 threads
// (240 active). Register-rolling vertical scan; LDS collect; counting-sort
// rank in-block; only the band-top-50 hits HBM. No cross-block traffic.
// ---------------------------------------------------------------------------
__global__ __launch_bounds__(256) void scanrank_kernel(
    const float* __restrict__ heat,
    float* __restrict__ ssc,    // [NPL*NSUB][64]
    int* __restrict__ spi,      // [NPL*NSUB][64]
    int* __restrict__ scnt) {   // [NPL*NSUB]
  const int blk = blockIdx.x;
  const int tid = threadIdx.x;
  const int plane = blk / NSUB;
  const int band = blk - plane * NSUB;
  const float* hp = heat + (size_t)plane * HWp;

  __shared__ unsigned long long s_key[CAPS];   // 4 KB raw candidates
  __shared__ unsigned long long c_key[CAPS];   // 4 KB grouped (aliases hist)
  __shared__ int cnt[RBK], suf[RBK], cur[RBK];
  __shared__ int s_n, s_B, s_above, s_T;

  if (tid == 0) s_n = 0;
  __syncthreads();

  // ---- collect >=TH peaks over this band (24 rows) ----
  band_scan(hp, band, tid, [&](unsigned int bits, int idx) {
    int slot = atomicAdd(&s_n, 1);
    if (slot < CAPS) s_key[slot] = mk_key(bits, idx);
  });
  __syncthreads();
  int n = s_n;

  if (n > CAPS) {
    // Overflow (>30-sigma event): raise the threshold via a two-level
    // histogram over [TH, 1.0) and recollect. Exact for the top-50.
    unsigned int* hist = (unsigned int*)c_key;   // 1024 u32 = 4 KB
    const unsigned int THB = __float_as_uint(TH_F);
    for (int i = tid; i < 1024; i += 256) hist[i] = 0;
    __syncthreads();
    band_scan(hp, band, tid, [&](unsigned int bits, int idx) {
      atomicAdd(&hist[(bits - THB) >> 7], 1u);   // <= 655
    });
    __syncthreads();
    if (tid == 0) {
      int acc = 0, res = 0, above = 0;
      for (int q = 655; q >= 0; --q) {
        int cc = (int)hist[q];
        if (acc + cc >= KTOP) { res = q; above = acc; break; }
        acc += cc;
      }
      s_B = res; s_above = above;
    }
    __syncthreads();
    const int Bc = s_B;
    for (int i = tid; i < 1024; i += 256) hist[i] = 0;
    __syncthreads();
    band_scan(hp, band, tid, [&](unsigned int bits, int idx) {
      if ((int)((bits - THB) >> 7) == Bc)
        atomicAdd(&hist[(bits - THB) & 127], 1u);
    });
    __syncthreads();
    if (tid == 0) {
      int acc = s_above, S = 0;
      for (int sb = 127; sb >= 0; --sb) {
        int cc = (int)hist[sb];
        if (acc + cc >= KTOP) { S = sb; break; }
        acc += cc;
      }
      s_T = (int)(THB + ((unsigned int)Bc << 7) + (unsigned int)S);
      s_n = 0;
    }
    __syncthreads();
    const unsigned int T = (unsigned int)s_T;
    band_scan(hp, band, tid, [&](unsigned int bits, int idx) {
      if (bits >= T) {
        int slot = atomicAdd(&s_n, 1);
        if (slot < CAPS) s_key[slot] = mk_key(bits, idx);
      }
    });
    __syncthreads();
    n = s_n < CAPS ? s_n : CAPS;
  }

  // ---- O(n) counting-sort rank: (value desc, idx asc). ----
  cnt[tid] = 0;
  cur[tid] = 0;
  __syncthreads();
  for (int i = tid; i < n; i += 256)
    atomicAdd(&cnt[bucket_of((unsigned int)(s_key[i] >> 32))], 1);
  __syncthreads();
  suf[tid] = cnt[tid];
  __syncthreads();
#pragma unroll
  for (int d = 1; d < RBK; d <<= 1) {
    const int v = (tid + d < RBK) ? suf[tid + d] : 0;
    __syncthreads();
    suf[tid] += v;
    __syncthreads();
  }
  {
    const int excl = suf[tid] - cnt[tid];   // keys in buckets > tid
    __syncthreads();
    suf[tid] = excl;
  }
  __syncthreads();
  for (int i = tid; i < n; i += 256) {
    const unsigned long long k = s_key[i];
    const int bq = bucket_of((unsigned int)(k >> 32));
    const int slot = suf[bq] + atomicAdd(&cur[bq], 1);
    c_key[slot] = k;
  }
  __syncthreads();
  float* psc = ssc + blk * 64;
  int* ppi = spi + blk * 64;
  for (int i = tid; i < n; i += 256) {
    const unsigned long long k = c_key[i];
    const int bq = bucket_of((unsigned int)(k >> 32));
    const int st = suf[bq];
    const int nb = cnt[bq];
    int rank = st;
    for (int tt = st; tt < st + nb; ++tt) rank += (c_key[tt] > k);
    if (rank < KTOP) {
      psc[rank] = __uint_as_float((unsigned int)(k >> 32));
      ppi[rank] = (int)~((unsigned int)k);
    }
  }
  for (int s2 = n + tid; s2 < KTOP; s2 += 256) {
    psc[s2] = 0.0f;
    ppi[s2] = 0;
  }
  if (tid == 0) scnt[blk] = n;
}

// ---------------------------------------------------------------------------
// Kernel 2: merge + top-50 + 3D decode. 32 blocks x 256 threads.
// Batch top-50 == top-50 of the 1200 merged composed keys (score desc,
// cls asc, idx asc), via bucketed counting-sort (no dependent-branch LDS
// chains — R5's 88 µs lesson).
// ---------------------------------------------------------------------------
__global__ __launch_bounds__(256) void decode_kernel(
    const float* __restrict__ heat,
    const float* __restrict__ ssc,
    const int* __restrict__ spi,
    const int* __restrict__ scnt,
    const float* __restrict__ regr,      // [B][8][HWp]
    const float* __restrict__ trans_mat, // [B][3][3]
    const float* __restrict__ K_mat,     // [B][3][3]
    const float* __restrict__ img_size,  // [B][2]
    float* __restrict__ out) {           // [B*50][14]
  const int b = blockIdx.x;
  const int tid = threadIdx.x;

  __shared__ unsigned long long d_keys[NMERGE];     // 9.6 KB merged keys
  __shared__ unsigned long long g_keys[NMERGE];     // 9.6 KB bucket-grouped
  __shared__ int cnt[RBK], suf[RBK], cur[RBK];
  __shared__ int sel[KTOP];
  __shared__ int s_ctl[NCLS * NSUB];
  __shared__ int s_ct[NCLS];
  // fallback scratch (exact whole-plane rescan; never fires on this data)
  __shared__ unsigned long long s_key[CAP];         // 16 KB
  __shared__ unsigned long long c_key[CAP];         // 16 KB (hist alias)
  __shared__ int s_fbB, s_fbAbove, s_fbT, s_fbCnt;

  // true per-class >=TH candidate totals (parallel load, then tiny reduce)
  if (tid < NCLS * NSUB) s_ctl[tid] = scnt[b * NCLS * NSUB + tid];
  __syncthreads();
  if (tid < NCLS) {
    int t = 0;
#pragma unroll
    for (int s = 0; s < NSUB; ++s) t += s_ctl[tid * NSUB + s];
    s_ct[tid] = t;
  }
  __syncthreads();

  // build merged composed keys from the 24 band-top-50 lists
  for (int i = tid; i < NMERGE; i += 256) {
    const int c = i / (NSUB * KTOP);
    const int rem = i - c * (NSUB * KTOP);
    const int s = rem / KTOP;
    const int k2 = rem - s * KTOP;
    const int sb = (b * NCLS + c) * NSUB + s;
    const float v = ssc[sb * 64 + k2];
    const int idx = spi[sb * 64 + k2];
    d_keys[i] = mk_key19(__float_as_uint(v), c, idx);
  }
  __syncthreads();

  // per-class exactness fallback: plane has <50 peaks >= TH -> exact rescan
  for (int c = 0; c < NCLS; ++c) {
    if (s_ct[c] < KTOP) {
      const float* hp = heat + (size_t)(b * NCLS + c) * HWp;
      unsigned int* fb_hist = (unsigned int*)c_key;
      for (int i = tid; i < 1024; i += 256) fb_hist[i] = 0;
      __syncthreads();
      for_each_peak_plane(hp, tid, 256, [&](unsigned int bits, int idx) {
        unsigned int bkt = bits >> 20; if (bkt > 1023u) bkt = 1023u;
        atomicAdd(&fb_hist[bkt], 1u);
      });
      __syncthreads();
      if (tid == 0) {
        int acc = 0, Bs = -1;
        for (int bkt = 1023; bkt >= 0; --bkt) {
          int cc = (int)fb_hist[bkt];
          if (acc + cc >= KTOP) { Bs = bkt; s_fbAbove = acc; break; }
          acc += cc;
        }
        s_fbB = Bs;
        if (Bs < 0) s_fbAbove = acc;
      }
      __syncthreads();
      const int Bs = s_fbB;
      unsigned int T;
      if (Bs < 0) {
        T = 0;  // fewer than 50 peaks total: take them all
      } else {
        for (int i = tid; i < 1024; i += 256) fb_hist[i] = 0;
        __syncthreads();
        for_each_peak_plane(hp, tid, 256, [&](unsigned int bits, int idx) {
          unsigned int bkt = bits >> 20; if (bkt > 1023u) bkt = 1023u;
          if ((int)bkt == Bs) atomicAdd(&fb_hist[(bits >> 10) & 1023], 1u);
        });
        __syncthreads();
        if (tid == 0) {
          int acc = s_fbAbove, Ss = 0;
          for (int sb = 1023; sb >= 0; --sb) {
            int cc = (int)fb_hist[sb];
            if (acc + cc >= KTOP) { Ss = sb; break; }
            acc += cc;
          }
          s_fbT = (int)(((unsigned int)Bs << 20) | ((unsigned int)Ss << 10));
        }
        __syncthreads();
        T = (unsigned int)s_fbT;
      }
      if (tid == 0) s_fbCnt = 0;
      __syncthreads();
      for_each_peak_plane(hp, tid, 256, [&](unsigned int bits, int idx) {
        if (bits >= T) {
          int slot = atomicAdd(&s_fbCnt, 1);
          if (slot < CAP) s_key[slot] = mk_key(bits, idx);
        }
      });
      __syncthreads();
      const int M = s_fbCnt < CAP ? s_fbCnt : CAP;
      // rank M keys, write class-c top-50 into its d_keys slice
      cnt[tid] = 0; cur[tid] = 0;
      __syncthreads();
      for (int i = tid; i < M; i += 256)
        atomicAdd(&cnt[bucket_of((unsigned int)(s_key[i] >> 32))], 1);
      __syncthreads();
      suf[tid] = cnt[tid];
      __syncthreads();
#pragma unroll
      for (int d = 1; d < RBK; d <<= 1) {
        const int v = (tid + d < RBK) ? suf[tid + d] : 0;
        __syncthreads();
        suf[tid] += v;
        __syncthreads();
      }
      {
        const int excl = suf[tid] - cnt[tid];
        __syncthreads();
        suf[tid] = excl;
      }
      __syncthreads();
      for (int i = tid; i < M; i += 256) {
        const unsigned long long k = s_key[i];
        const int bq = bucket_of((unsigned int)(k >> 32));
        const int slot = suf[bq] + atomicAdd(&cur[bq], 1);
        c_key[slot] = k;
      }
      __syncthreads();
      for (int i = tid; i < NSUB * KTOP; i += 256)   // clear class slice
        d_keys[c * (NSUB * KTOP) + i] = mk_key19(0u, c, 0);
      __syncthreads();
      for (int i = tid; i < M; i += 256) {
        const unsigned long long k = c_key[i];
        const int bq = bucket_of((unsigned int)(k >> 32));
        const int st = suf[bq];
        const int nb = cnt[bq];
        int rank = st;
        for (int tt = st; tt < st + nb; ++tt) rank += (c_key[tt] > k);
        if (rank < KTOP)
          d_keys[c * (NSUB * KTOP) + rank] =
              mk_key19((unsigned int)(k >> 32), c, (int)~((unsigned int)k));
      }
      __syncthreads();
    }
  }

  // ---- top-50 of the 1200 composed keys via bucketed counting-sort ----
  cnt[tid] = 0;
  cur[tid] = 0;
  __syncthreads();
  for (int i = tid; i < NMERGE; i += 256)
    atomicAdd(&cnt[bucket_of((unsigned int)(d_keys[i] >> 19))], 1);
  __syncthreads();
  suf[tid] = cnt[tid];
  __syncthreads();
#pragma unroll
  for (int d = 1; d < RBK; d <<= 1) {
    const int v = (tid + d < RBK) ? suf[tid + d] : 0;
    __syncthreads();
    suf[tid] += v;
    __syncthreads();
  }
  {
    const int excl = suf[tid] - cnt[tid];   // keys in buckets > tid
    __syncthreads();
    suf[tid] = excl;
  }
  __syncthreads();
  for (int i = tid; i < NMERGE; i += 256) {
    const unsigned long long k = d_keys[i];
    const int bq = bucket_of((unsigned int)(k >> 19));
    const int slot = suf[bq] + atomicAdd(&cur[bq], 1);
    g_keys[slot] = k;
  }
  __syncthreads();
  for (int i = tid; i < NMERGE; i += 256) {
    const unsigned long long k = g_keys[i];
    const int bq = bucket_of((unsigned int)(k >> 19));
    const int st = suf[bq];
    if (st >= KTOP) continue;   // whole bucket below top-50 (prunes padding)
    const int nb = cnt[bq];
    int rank = st;
    for (int tt = st; tt < st + nb; ++tt) rank += (g_keys[tt] > k);
    if (rank < KTOP) sel[rank] = i;
  }
  __syncthreads();

  if (tid < KTOP) {
    const unsigned long long k = g_keys[sel[tid]];
    const float score = __uint_as_float((unsigned int)(k >> 19));
    const int cls = 2 - (int)((k >> 17) & 3);
    const int ind = ((int)(k & 0x1FFFF)) ^ 0x1FFFF;
    const float ys = (float)(ind / Wd);
    const float xs = (float)(ind - (ind / Wd) * Wd);

    const float* rb = regr + (size_t)b * 8 * HWp + ind;
    const float r0 = rb[0 * HWp], r1 = rb[1 * HWp], r2 = rb[2 * HWp], r3 = rb[3 * HWp];
    const float r4 = rb[4 * HWp], r5 = rb[5 * HWp], r6 = rb[6 * HWp], r7 = rb[7 * HWp];

    float tm[9], km[9], tmi[9], kmi[9];
#pragma unroll
    for (int q = 0; q < 9; ++q) { tm[q] = trans_mat[b * 9 + q]; km[q] = K_mat[b * 9 + q]; }
    inv3(tm, tmi);
    inv3(km, kmi);

    const float px = xs + r1, py = ys + r2;
    const float gx = tmi[0] * px + tmi[1] * py + tmi[2];
    const float gy = tmi[3] * px + tmi[4] * py + tmi[5];
    const float gz = tmi[6] * px + tmi[7] * py + tmi[8];
    const float depth = r0 * 16.32f + 28.01f;
    const float qx = gx * depth, qy = gy * depth, qz = gz * depth;
    const float lx = kmi[0] * qx + kmi[1] * qy + kmi[2] * qz;
    float ly = kmi[3] * qx + kmi[4] * qy + kmi[5] * qz;
    const float lz = kmi[6] * qx + kmi[7] * qy + kmi[8] * qz;

    const float d0 = expf(r3) * DIM_REF_C[cls * 3 + 0];
    const float d1 = expf(r4) * DIM_REF_C[cls * 3 + 1];
    const float d2 = expf(r5) * DIM_REF_C[cls * 3 + 2];
    ly += d1 * 0.5f;

    const float ray = atanf(lx / (lz + 1e-7f));
    float alpha = atanf(r6 / (r7 + 1e-7f));
    alpha += (r7 >= 0.0f) ? -PI_F * 0.5f : PI_F * 0.5f;
    const float roty = wrap_pi(alpha + ray);
    alpha = wrap_pi(alpha);

    const float SX[8] = {-0.5f, 0.5f, 0.5f, 0.5f, 0.5f, -0.5f, -0.5f, -0.5f};
    const float SY[8] = {-1.0f, -1.0f, 0.0f, 0.0f, -1.0f, -1.0f, 0.0f, 0.0f};
    const float SZ[8] = {-0.5f, -0.5f, -0.5f, 0.5f, 0.5f, 0.5f, 0.5f, -0.5f};
    const float cr = cosf(roty), sr = sinf(roty);
    float minx = INFINITY, maxx = -INFINITY, miny = INFINITY, maxy = -INFINITY;
#pragma unroll
    for (int j = 0; j < 8; ++j) {
      const float ax = d0 * SX[j], ay = d1 * SY[j], az = d2 * SZ[j];
      const float cx = cr * ax + sr * az + lx;
      const float cy = ay + ly;
      const float cz = -sr * ax + cr * az + lz;
      const float ppx = km[0] * cx + km[1] * cy + km[2] * cz;
      const float ppy = km[3] * cx + km[4] * cy + km[5] * cz;
      const float ppz = km[6] * cx + km[7] * cy + km[8] * cz;
      const float X = ppx / ppz, Y = ppy / ppz;
      minx = fminf(minx, X); maxx = fmaxf(maxx, X);
      miny = fminf(miny, Y); maxy = fmaxf(maxy, Y);
    }
    const float Wi = img_size[b * 2 + 0], Hi = img_size[b * 2 + 1];
    const float xmin = fminf(fmaxf(minx, 0.0f), Wi);
    const float ymin = fminf(fmaxf(miny, 0.0f), Hi);
    const float xmax = fminf(fmaxf(maxx, 0.0f), Wi);
    const float ymax = fminf(fmaxf(maxy, 0.0f), Hi);

    float* o = out + (size_t)(b * KTOP + tid) * 14;
    if (score > 0.25f) {
      o[0] = (float)cls; o[1] = alpha;
      o[2] = xmin; o[3] = ymin; o[4] = xmax; o[5] = ymax;
      o[6] = d1; o[7] = d2; o[8] = d0;   // dims rolled by -1
      o[9] = lx; o[10] = ly; o[11] = lz;
      o[12] = roty; o[13] = score;
    } else {
#pragma unroll
      for (int q = 0; q < 14; ++q) o[q] = 0.0f;
    }
  }
}

// ---------------------------------------------------------------------------

extern "C" void kernel_launch(void* const* d_in, const int* in_sizes, int n_in,
                              void* d_out, int out_size, void* d_ws, size_t ws_size,
                              hipStream_t stream) {
  const float* heat = (const float*)d_in[0];  // [32,3,192,640]
  const float* regr = (const float*)d_in[1];  // [32,8,192,640]
  const float* tmat = (const float*)d_in[2];  // [32,3,3]
  const float* kmat = (const float*)d_in[3];  // [32,3,3]
  const float* isz = (const float*)d_in[4];   // [32,2]

  char* ws = (char*)d_ws;
  float* ssc = (float*)(ws + OFF_SSC);
  int* spi = (int*)(ws + OFF_SPI);
  int* scnt = (int*)(ws + OFF_SCNT);

  scanrank_kernel<<<NPL * NSUB, 256, 0, stream>>>(heat, ssc, spi, scnt);
  decode_kernel<<<NB, 256, 0, stream>>>(heat, ssc, spi, scnt,
                                        regr, tmat, kmat, isz,
                                        (float*)d_out);
}